// Round 22
// baseline (107.342 us; speedup 1.0000x reference)
//
#include <hip/hip_runtime.h>
#include <stdint.h>
#include <stddef.h>
#include <math.h>

#define DEVINL __device__ __forceinline__

typedef __attribute__((ext_vector_type(8))) __bf16 bf16x8;
typedef __attribute__((ext_vector_type(4))) float f32x4;
typedef __attribute__((ext_vector_type(4))) unsigned short us4;
typedef __attribute__((ext_vector_type(8))) unsigned short us8;
typedef __attribute__((ext_vector_type(4))) short short4v;  // K=16 MFMA A/B operand

typedef __attribute__((address_space(1))) unsigned int as1_uint;
typedef __attribute__((address_space(3))) unsigned int as3_uint;

constexpr int SEQ    = 2048;
constexpr int DMODEL = 1024;
constexpr int MTOT   = 4096;    // B*L
constexpr int NQKV   = 3072;
constexpr int DKH    = 64;

// workspace layout (bytes)
constexpr size_t OFF_XBF  = 0;                                      // 8 MiB
constexpr size_t OFF_WQKV = OFF_XBF  + (size_t)MTOT * DMODEL * 2;   // 6 MiB
constexpr size_t OFF_WOUT = OFF_WQKV + (size_t)NQKV * DMODEL * 2;   // 2 MiB
constexpr size_t OFF_Q    = OFF_WOUT + (size_t)DMODEL * DMODEL * 2; // 8 MiB
constexpr size_t OFF_K    = OFF_Q    + (size_t)MTOT * DMODEL * 2;   // 8 MiB
constexpr size_t OFF_VT   = OFF_K    + (size_t)MTOT * DMODEL * 2;   // 8 MiB
constexpr size_t OFF_O    = OFF_VT   + (size_t)MTOT * DMODEL * 2;   // 8 MiB
constexpr size_t OFF_ROPE = OFF_O    + (size_t)MTOT * DMODEL * 2;   // 1 MiB

// Q pre-scale: 1/sqrt(64) * log2(e) -> softmax runs in exp2 domain
constexpr float QSCALE = 0.125f * 1.4426950408889634f;

DEVINL unsigned short f2bf(float f) {
  unsigned int u = __float_as_uint(f);
  u += 0x7fffu + ((u >> 16) & 1u);
  return (unsigned short)(u >> 16);
}

DEVINL float fexp2(float x) { return __builtin_amdgcn_exp2f(x); }  // 1x v_exp_f32

DEVINL void gld_lds16(const unsigned short* g, unsigned short* s) {
  __builtin_amdgcn_global_load_lds((as1_uint*)g, (as3_uint*)s, 16, 0, 0);
}

// ---------------- prep: fp32->bf16 converts + rope table ----------------
__global__ __launch_bounds__(256) void prep_kernel(
    const float* __restrict__ X, const float* __restrict__ Wqkv,
    const float* __restrict__ Wout, const int* __restrict__ pos,
    unsigned short* __restrict__ xbf, unsigned short* __restrict__ wqkvbf,
    unsigned short* __restrict__ woutbf, float2* __restrict__ rope) {
  const int t = blockIdx.x * 256 + threadIdx.x;
  if (t < MTOT * 32) {  // rope table: (m, pair)
    const int m = t >> 5, ip = t & 31;
    const float freq = powf(10000.0f, -(float)(2 * ip) / 64.0f);
    const float ang = (float)pos[m] * freq;
    float sv, cv;
    sincosf(ang, &sv, &cv);
    rope[t] = make_float2(cv, sv);
  }
  const int NX = MTOT * DMODEL, NW1 = NQKV * DMODEL, NW2 = DMODEL * DMODEL;
  const int e = t * 4;
  const float* src;
  unsigned short* dst;
  if (e < NX) { src = X + e; dst = xbf + e; }
  else if (e < NX + NW1) { src = Wqkv + (e - NX); dst = wqkvbf + (e - NX); }
  else if (e < NX + NW1 + NW2) { src = Wout + (e - NX - NW1); dst = woutbf + (e - NX - NW1); }
  else return;
  const float4 v = *(const float4*)src;
  us4 o = { f2bf(v.x), f2bf(v.y), f2bf(v.z), f2bf(v.w) };
  *(us4*)dst = o;
}

// ---------------- GEMM: producer-consumer wave specialization ----------------
// (round-20 proven; unchanged). 512 threads = 8 waves: waves 0-3 consumers
// (round-13 fragment math), waves 4-7 producers (round-13 staging geometry).
// Double-buffered BK=64; producers fill buf^1 while consumers compute buf;
// __syncthreads makes each group wait only on ITS OWN counters.
template <int MODE>
__global__ __launch_bounds__(512) void gemm_kernel(
    const unsigned short* __restrict__ A, const unsigned short* __restrict__ Bw,
    unsigned short* __restrict__ q_out, unsigned short* __restrict__ k_out,
    unsigned short* __restrict__ vt_out, const float2* __restrict__ rope,
    float* __restrict__ f_out) {
  constexpr int K = DMODEL;  // 1024
  __shared__ __align__(16) unsigned short As[2][2][128 * 32];  // [buf][kk] 32KB
  __shared__ __align__(16) unsigned short Bs[2][2][128 * 32];  // 32KB
  const int tid = threadIdx.x;
  const int l = tid & 63, w = tid >> 6;       // w 0..7
  const bool producer = (w >= 4);
  const int w4 = w & 3;                       // consumer wave id / producer id
  const int g = l >> 4, l15 = l & 15;

  // XCD-chunked swizzle (bijective)
  constexpr int GX  = (MODE == 0) ? 24 : 8;   // gridDim.x (n-blocks)
  constexpr int CHN = (MODE == 0) ? 12 : 4;   // n-blocks per XCD chunk
  const int lid = blockIdx.x + GX * blockIdx.y;
  const int xcd = lid & 7;
  const int sc  = lid >> 3;                   // slot in chunk
  const int bm = (xcd & 3) * 8 + (sc & 7);
  const int bn = (xcd >> 2) * CHN + (sc >> 3);
  const int m0 = bm * 128, n0 = bn * 128;
  const int wm = w4 >> 1, wn = w4 & 1;

  // producer staging addresses (round-13 geometry with pw = w4)
  const unsigned short* ag = A  + (size_t)(m0 + w4 * 16 + (l >> 2)) * K + (l & 3) * 8;
  const unsigned short* bg = Bw + (size_t)(n0 + w4 * 16 + (l >> 2)) * K + (l & 3) * 8;

  auto STAGE = [&](int bb, int kt) {
#pragma unroll
    for (int kk = 0; kk < 2; ++kk) {
      const unsigned short* a0 = ag + kt * 64 + kk * 32;
      const unsigned short* b0 = bg + kt * 64 + kk * 32;
      unsigned short* as0 = &As[bb][kk][0] + w4 * 512;
      unsigned short* bs0 = &Bs[bb][kk][0] + w4 * 512;
      gld_lds16(a0, as0);
      gld_lds16(a0 + (size_t)64 * K, as0 + 2048);
      gld_lds16(b0, bs0);
      gld_lds16(b0 + (size_t)64 * K, bs0 + 2048);
    }
  };

  const f32x4 zf = {0.f, 0.f, 0.f, 0.f};
  f32x4 acc[4][4];
#pragma unroll
  for (int i = 0; i < 4; ++i)
#pragma unroll
    for (int j = 0; j < 4; ++j) acc[i][j] = zf;

  if (producer) STAGE(0, 0);
  __syncthreads();
  int cur = 0;

  for (int kt = 0; kt < K / 64; ++kt) {
    if (producer) {
      if (kt + 1 < K / 64) STAGE(cur ^ 1, kt + 1);
    } else {
      bf16x8 af[4][2], bf[4][2];
#pragma unroll
      for (int i = 0; i < 4; ++i)
#pragma unroll
        for (int kk = 0; kk < 2; ++kk) {
          af[i][kk] = *(const bf16x8*)(&As[cur][kk][0] + (wm * 64 + i * 16 + l15) * 32 + g * 8);
          bf[i][kk] = *(const bf16x8*)(&Bs[cur][kk][0] + (wn * 64 + i * 16 + l15) * 32 + g * 8);
        }
#pragma unroll
      for (int i = 0; i < 4; ++i)
#pragma unroll
        for (int j = 0; j < 4; ++j) {
          acc[i][j] = __builtin_amdgcn_mfma_f32_16x16x32_bf16(af[i][0], bf[j][0], acc[i][j], 0, 0, 0);
          acc[i][j] = __builtin_amdgcn_mfma_f32_16x16x32_bf16(af[i][1], bf[j][1], acc[i][j], 0, 0, 0);
        }
    }
    __syncthreads();
    cur ^= 1;
  }

  if (producer) return;   // epilogue is consumer-only (waves 0-3 hold acc)

  if constexpr (MODE == 0) {
    const int region = n0 >> 10;  // 0=Q 1=K 2=V (128 | 1024 region boundaries)
    if (region <= 1) {
      unsigned short* outb = (region == 0) ? q_out : k_out;
      const float qs = (region == 0) ? QSCALE : 1.0f;
#pragma unroll
      for (int i = 0; i < 4; ++i) {
        const int mb = m0 + wm * 64 + i * 16 + g * 4;
#pragma unroll
        for (int j = 0; j < 4; ++j) {
          const int n = n0 + wn * 64 + j * 16 + l15;
          const int ncol = n & 1023;
          const int ip = (n & 63) >> 1;
          const float sgn = (n & 1) ? 1.f : -1.f;
#pragma unroll
          for (int r = 0; r < 4; ++r) {
            const int m = mb + r;
            const float v = acc[i][j][r];
            const float p = __shfl_xor(v, 1);  // partner column n^1
            const float2 cs = rope[m * 32 + ip];
            const float o = (v * cs.x + sgn * p * cs.y) * qs;
            outb[(size_t)m * DMODEL + ncol] = f2bf(o);
          }
        }
      }
    } else {  // V -> transposed per head: Vt[(b*1024 + h*64 + d)][l]
#pragma unroll
      for (int i = 0; i < 4; ++i) {
        const int mb = m0 + wm * 64 + i * 16 + g * 4;
        const int b = mb >> 11;
        const int lseq = mb & 2047;
#pragma unroll
        for (int j = 0; j < 4; ++j) {
          const int n = n0 + wn * 64 + j * 16 + l15;
          const int hd = n - 2048;
          us4 o = { f2bf(acc[i][j][0]), f2bf(acc[i][j][1]), f2bf(acc[i][j][2]), f2bf(acc[i][j][3]) };
          *(us4*)(vt_out + (size_t)(b * DMODEL + hd) * SEQ + lseq) = o;
        }
      }
    }
  } else {
#pragma unroll
    for (int i = 0; i < 4; ++i) {
      const int mb = m0 + wm * 64 + i * 16 + g * 4;
#pragma unroll
      for (int j = 0; j < 4; ++j) {
        const int n = n0 + wn * 64 + j * 16 + l15;
#pragma unroll
        for (int r = 0; r < 4; ++r) f_out[(size_t)(mb + r) * DMODEL + n] = acc[i][j][r];
      }
    }
  }
}

// ---------------- causal flash attention v14: producer-consumer + depth-2 ----------------
// v13 + TRIPLE-BUFFERED kv with counted producer waits: producer stages tile
// s+2 each iteration, then waits vmcnt(4) (tile s+1 certified; tile s+2's 4
// loads stay IN FLIGHT across the raw s_barrier); consumers wait only
// lgkmcnt(0). The phase-switch STORE barrier is lgkm-only too -> the
// producers' pipeline NEVER drains mid-kernel (v13's per-iteration
// __syncthreads forced producer vmcnt(0) each tile).
// Hazards: producer writes buf (s+2)%3, last read at seq s-1 whose
// lgkm-wait+barrier precede the write; consumer reads buf s%3 certified by
// the vmcnt(4) at barrier s-1.
__global__ __launch_bounds__(512) void attn_kernel(
    const unsigned short* __restrict__ Qb, const unsigned short* __restrict__ Kb,
    const unsigned short* __restrict__ Vt, unsigned short* __restrict__ Ob) {
  __shared__ __align__(16) unsigned short kv[3][2][4096];  // 48KB triple buffer
  __shared__ __align__(16) unsigned short Olds[4][16][72]; // 9KB
  const int tid = threadIdx.x;
  const int l = tid & 63;
  const int wfull = tid >> 6;            // 0..7
  const bool producer = (wfull >= 4);
  const int w = wfull & 3;               // q-subtile (consumer) / producer id
  const int g = l >> 4, q15 = l & 15;
  const int ptid = tid & 255;            // staging thread id (producers)

  // XCD-affinity remap (bijective): blocks of one bh share lid mod 8
  const int lid = blockIdx.x + 16 * blockIdx.y;   // 0..511
  const int xcd = lid & 7;
  const int slot = lid >> 3;                      // 0..63
  const int bh = xcd * 4 + (slot & 3);            // 0..31
  const int j = slot >> 2;                        // 0..15

  const int b = bh >> 4, h = bh & 15;
  const int tA = 31 - j;            // long phase q-tile (>= 16)
  const int tB = j;                 // short phase q-tile

  // Q fragments for both phases (consumers only)
  bf16x8 qA0{}, qA1{}, qB0{}, qB1{};
  if (!producer) {
    const unsigned short* qpA = Qb + (size_t)(b * SEQ + tA * 64 + w * 16 + q15) * DMODEL + h * DKH + g * 8;
    const unsigned short* qpB = Qb + (size_t)(b * SEQ + tB * 64 + w * 16 + q15) * DMODEL + h * DKH + g * 8;
    qA0 = *(const bf16x8*)qpA; qA1 = *(const bf16x8*)(qpA + 32);
    qB0 = *(const bf16x8*)qpB; qB1 = *(const bf16x8*)(qpB + 32);
  }
  const int qselA = tA * 64 + w * 16 + q15;
  const int qselB = tB * 64 + w * 16 + q15;

  // staging source (pre-swizzled), producers only
  const int rS = ptid >> 3;                                       // rows 0..31 (+32)
  const int cS = (((ptid & 7) * 16) ^ ((rS & 7) << 4)) >> 1;      // element col
  const unsigned short* pKg = Kb + (size_t)(b * SEQ + rS) * DMODEL + h * DKH + cS;
  const unsigned short* pVg = Vt + (size_t)(b * DMODEL + h * DKH + rS) * SEQ + cS;

  // swizzled ds_read offsets (elements), reading row has row&7 == q15&7
  const int srow = (q15 & 7) << 4;
  const int oc0 = (srow ^ (g * 16)) >> 1;          // K frag: d-slice g*8..g*8+7
  const int oc1 = (srow ^ (g * 16 + 64)) >> 1;
  // V frag (K=16 A-operand): per blk, 8 bytes at col blk*32 + 8g
  int vc[4];
#pragma unroll
  for (int blk = 0; blk < 4; ++blk) vc[blk] = ((blk * 32 + 8 * g) ^ srow) >> 1;

  const f32x4 zf = {0.f, 0.f, 0.f, 0.f};
  float mrun = -1e30f, lrun = 0.f;   // lrun = per-lane partial row sum
  f32x4 ot[4];
#pragma unroll
  for (int d = 0; d < 4; ++d) ot[d] = zf;

  auto KN = [&](int s) { return (s <= tA) ? s : (s - tA - 1); };

  auto STAGE = [&](int bb, int k0) {   // producers only
    unsigned short* lk = &kv[bb][0][0] + w * 512;  // wave-uniform base (w = producer id)
    unsigned short* lv = &kv[bb][1][0] + w * 512;
    gld_lds16(pKg + (size_t)k0 * DMODEL, lk);
    gld_lds16(pKg + (size_t)(k0 + 32) * DMODEL, lk + 2048);
    gld_lds16(pVg + k0, lv);
    gld_lds16(pVg + (size_t)32 * SEQ + k0, lv + 2048);
  };

  // per-iteration barrier with per-role waits; s = sequence position (uniform)
  auto BAR = [&](int s) {
    if (producer) {
      if (s + 2 < 33) asm volatile("s_waitcnt vmcnt(4)" ::: "memory");
      else            asm volatile("s_waitcnt vmcnt(0)" ::: "memory");
    } else {
      asm volatile("s_waitcnt lgkmcnt(0)" ::: "memory");
    }
    __builtin_amdgcn_sched_barrier(0);
    __builtin_amdgcn_s_barrier();
    __builtin_amdgcn_sched_barrier(0);
  };

  auto STORE = [&](int qt) {           // role-aware; lgkm-only internal barrier
    if (!producer) {
      float lr = lrun;
      lr += __shfl_xor(lr, 16);
      lr += __shfl_xor(lr, 32);
      const float inv = 1.0f / lr;
#pragma unroll
      for (int d = 0; d < 4; ++d) {
        us4 o = { f2bf(ot[d][0] * inv), f2bf(ot[d][1] * inv), f2bf(ot[d][2] * inv), f2bf(ot[d][3] * inv) };
        *(us4*)&Olds[w][q15][d * 16 + g * 4] = o;
      }
    }
    asm volatile("s_waitcnt lgkmcnt(0)" ::: "memory");
    __builtin_amdgcn_sched_barrier(0);
    __builtin_amdgcn_s_barrier();
    __builtin_amdgcn_sched_barrier(0);
    if (!producer) {
      const int r = l >> 2;
      const int c = (l & 3) * 16;
      const us8 v0 = *(const us8*)&Olds[w][r][c];
      const us8 v1 = *(const us8*)&Olds[w][r][c + 8];
      unsigned short* ob = Ob + (size_t)(b * SEQ + qt * 64 + w * 16 + r) * DMODEL + h * DKH + c;
      *(us8*)ob = v0;
      *(us8*)(ob + 8) = v1;
    }
  };

  // one k-tile: QK^T -> online softmax -> in-lane P pack -> K=16 PV.
  auto ITER = [&](int cur, int kb0, bf16x8 qf0, bf16x8 qf1, int qsel, bool domask) {
    const unsigned short* lkb = &kv[cur][0][0] + q15 * 64;
    const unsigned short* lvb = &kv[cur][1][0] + q15 * 64;

    float sp[4][4];
    float mt = -1e30f;
#pragma unroll
    for (int blk = 0; blk < 4; ++blk) {
      const bf16x8 kf0 = *(const bf16x8*)(lkb + blk * 1024 + oc0);
      const bf16x8 kf1 = *(const bf16x8*)(lkb + blk * 1024 + oc1);
      f32x4 c = zf;
      c = __builtin_amdgcn_mfma_f32_16x16x32_bf16(kf0, qf0, c, 0, 0, 0);
      c = __builtin_amdgcn_mfma_f32_16x16x32_bf16(kf1, qf1, c, 0, 0, 0);
#pragma unroll
      for (int r = 0; r < 4; ++r) {
        float s = c[r];  // already in exp2 domain (Q pre-scaled)
        if (domask && (kb0 + blk * 16 + g * 4 + r > qsel)) s = -1e30f;
        sp[blk][r] = s;
        mt = fmaxf(mt, s);
      }
    }
    mt = fmaxf(mt, __shfl_xor(mt, 16));
    mt = fmaxf(mt, __shfl_xor(mt, 32));

    const bool defer = __all(mt - mrun <= 8.0f);
    float mnew, alpha;
    if (defer) { mnew = mrun; alpha = 1.0f; }
    else { mnew = fmaxf(mrun, mt); alpha = fexp2(mrun - mnew); }

    float rs = 0.f;
#pragma unroll
    for (int blk = 0; blk < 4; ++blk)
#pragma unroll
      for (int r = 0; r < 4; ++r) {
        const float p = fexp2(sp[blk][r] - mnew);
        sp[blk][r] = p;
        rs += p;
      }
    if (defer) {
      lrun += rs;                 // per-lane partial; cross-lane reduce at STORE
    } else {
      lrun = lrun * alpha + rs;
      mrun = mnew;
#pragma unroll
      for (int d = 0; d < 4; ++d) ot[d] *= alpha;
    }

    // P -> bf16 K=16 B-fragments in-lane (no shuffles)
    short4v pfb[4];
#pragma unroll
    for (int blk = 0; blk < 4; ++blk) {
      union { __bf16 hh[4]; short4v v; } pk;
      pk.hh[0] = (__bf16)sp[blk][0];
      pk.hh[1] = (__bf16)sp[blk][1];
      pk.hh[2] = (__bf16)sp[blk][2];
      pk.hh[3] = (__bf16)sp[blk][3];
      pfb[blk] = pk.v;
    }

    // O^T[dt][q] += sum_blk Vt[16dt+q15][k(blk)] * P[k(blk)][q]  (K=16 MFMAs)
    __builtin_amdgcn_s_setprio(1);
#pragma unroll
    for (int dt = 0; dt < 4; ++dt) {
      const unsigned short* vrow = lvb + dt * 1024;
      f32x4 o = ot[dt];
#pragma unroll
      for (int blk = 0; blk < 4; ++blk) {
        const short4v vf = *(const short4v*)(vrow + vc[blk]);
        o = __builtin_amdgcn_mfma_f32_16x16x16bf16_1k(vf, pfb[blk], o, 0, 0, 0);
      }
      ot[dt] = o;
    }
    __builtin_amdgcn_s_setprio(0);
  };

  // prologue: stage tiles 0,1; certify tile 0 (tile 1 stays in flight)
  if (producer) {
    STAGE(0, 0);
    STAGE(1, KN(1) * 64);
    asm volatile("s_waitcnt vmcnt(4)" ::: "memory");
  }
  __builtin_amdgcn_sched_barrier(0);
  __builtin_amdgcn_s_barrier();
  __builtin_amdgcn_sched_barrier(0);

  int s = 0;
  // ---- phase A main (no mask) ----
  for (int i = 0; i < tA; ++i, ++s) {
    if (producer) { if (s + 2 < 33) STAGE((s + 2) % 3, KN(s + 2) * 64); }
    else ITER(s % 3, i * 64, qA0, qA1, qselA, false);
    BAR(s);
  }
  // ---- phase A diagonal (mask) ----
  if (producer) { if (s + 2 < 33) STAGE((s + 2) % 3, KN(s + 2) * 64); }
  else ITER(s % 3, tA * 64, qA0, qA1, qselA, true);
  STORE(tA);
  if (!producer) {
    mrun = -1e30f; lrun = 0.f;
#pragma unroll
    for (int d = 0; d < 4; ++d) ot[d] = zf;
  }
  BAR(s);
  ++s;

  // ---- phase B main (no mask) ----
  for (int i = 0; i < tB; ++i, ++s) {
    if (producer) { if (s + 2 < 33) STAGE((s + 2) % 3, KN(s + 2) * 64); }
    else ITER(s % 3, i * 64, qB0, qB1, qselB, false);
    BAR(s);
  }
  // ---- phase B diagonal (mask) ----  (s == 32: nothing left to stage)
  if (!producer) ITER(s % 3, tB * 64, qB0, qB1, qselB, true);
  STORE(tB);
}

// ---------------- launch ----------------
extern "C" void kernel_launch(void* const* d_in, const int* in_sizes, int n_in,
                              void* d_out, int out_size, void* d_ws, size_t ws_size,
                              hipStream_t stream) {
  const float* X = (const float*)d_in[0];
  const int* pos = (const int*)d_in[1];
  const float* Wqkv = (const float*)d_in[2];
  const float* Wout = (const float*)d_in[3];
  char* ws = (char*)d_ws;
  unsigned short* xbf    = (unsigned short*)(ws + OFF_XBF);
  unsigned short* wqkvbf = (unsigned short*)(ws + OFF_WQKV);
  unsigned short* woutbf = (unsigned short*)(ws + OFF_WOUT);
  unsigned short* qb     = (unsigned short*)(ws + OFF_Q);
  unsigned short* kbuf   = (unsigned short*)(ws + OFF_K);
  unsigned short* vt     = (unsigned short*)(ws + OFF_VT);
  unsigned short* ob     = (unsigned short*)(ws + OFF_O);
  float2* rope           = (float2*)(ws + OFF_ROPE);

  prep_kernel<<<8192, 256, 0, stream>>>(X, Wqkv, Wout, pos, xbf, wqkvbf, woutbf, rope);
  gemm_kernel<0><<<dim3(NQKV / 128, MTOT / 128), 512, 0, stream>>>(
      xbf, wqkvbf, qb, kbuf, vt, rope, nullptr);
  attn_kernel<<<dim3(16, 32), 512, 0, stream>>>(qb, kbuf, vt, ob);
  gemm_kernel<1><<<dim3(DMODEL / 128, MTOT / 128), 512, 0, stream>>>(
      ob, woutbf, nullptr, nullptr, nullptr, nullptr, (float*)d_out);
}

// Round 23
// 105.849 us; speedup vs baseline: 1.0141x; 1.0141x over previous
//
#include <hip/hip_runtime.h>
#include <stdint.h>
#include <stddef.h>
#include <math.h>

#define DEVINL __device__ __forceinline__

typedef __attribute__((ext_vector_type(8))) __bf16 bf16x8;
typedef __attribute__((ext_vector_type(4))) float f32x4;
typedef __attribute__((ext_vector_type(4))) unsigned short us4;
typedef __attribute__((ext_vector_type(8))) unsigned short us8;
typedef __attribute__((ext_vector_type(4))) short short4v;  // K=16 MFMA A/B operand

typedef __attribute__((address_space(1))) unsigned int as1_uint;
typedef __attribute__((address_space(3))) unsigned int as3_uint;

constexpr int SEQ    = 2048;
constexpr int DMODEL = 1024;
constexpr int MTOT   = 4096;    // B*L
constexpr int NQKV   = 3072;
constexpr int DKH    = 64;

// workspace layout (bytes)
constexpr size_t OFF_XBF  = 0;                                      // 8 MiB
constexpr size_t OFF_WQKV = OFF_XBF  + (size_t)MTOT * DMODEL * 2;   // 6 MiB
constexpr size_t OFF_WOUT = OFF_WQKV + (size_t)NQKV * DMODEL * 2;   // 2 MiB
constexpr size_t OFF_Q    = OFF_WOUT + (size_t)DMODEL * DMODEL * 2; // 8 MiB
constexpr size_t OFF_K    = OFF_Q    + (size_t)MTOT * DMODEL * 2;   // 8 MiB
constexpr size_t OFF_VT   = OFF_K    + (size_t)MTOT * DMODEL * 2;   // 8 MiB
constexpr size_t OFF_O    = OFF_VT   + (size_t)MTOT * DMODEL * 2;   // 8 MiB
constexpr size_t OFF_ROPE = OFF_O    + (size_t)MTOT * DMODEL * 2;   // 1 MiB

// Q pre-scale: 1/sqrt(64) * log2(e) -> softmax runs in exp2 domain
constexpr float QSCALE = 0.125f * 1.4426950408889634f;

DEVINL unsigned short f2bf(float f) {
  unsigned int u = __float_as_uint(f);
  u += 0x7fffu + ((u >> 16) & 1u);
  return (unsigned short)(u >> 16);
}

DEVINL float fexp2(float x) { return __builtin_amdgcn_exp2f(x); }  // 1x v_exp_f32

DEVINL void gld_lds16(const unsigned short* g, unsigned short* s) {
  __builtin_amdgcn_global_load_lds((as1_uint*)g, (as3_uint*)s, 16, 0, 0);
}

// ---------------- prep: fp32->bf16 converts + rope table ----------------
__global__ __launch_bounds__(256) void prep_kernel(
    const float* __restrict__ X, const float* __restrict__ Wqkv,
    const float* __restrict__ Wout, const int* __restrict__ pos,
    unsigned short* __restrict__ xbf, unsigned short* __restrict__ wqkvbf,
    unsigned short* __restrict__ woutbf, float2* __restrict__ rope) {
  const int t = blockIdx.x * 256 + threadIdx.x;
  if (t < MTOT * 32) {  // rope table: (m, pair)
    const int m = t >> 5, ip = t & 31;
    const float freq = powf(10000.0f, -(float)(2 * ip) / 64.0f);
    const float ang = (float)pos[m] * freq;
    float sv, cv;
    sincosf(ang, &sv, &cv);
    rope[t] = make_float2(cv, sv);
  }
  const int NX = MTOT * DMODEL, NW1 = NQKV * DMODEL, NW2 = DMODEL * DMODEL;
  const int e = t * 4;
  const float* src;
  unsigned short* dst;
  if (e < NX) { src = X + e; dst = xbf + e; }
  else if (e < NX + NW1) { src = Wqkv + (e - NX); dst = wqkvbf + (e - NX); }
  else if (e < NX + NW1 + NW2) { src = Wout + (e - NX - NW1); dst = woutbf + (e - NX - NW1); }
  else return;
  const float4 v = *(const float4*)src;
  us4 o = { f2bf(v.x), f2bf(v.y), f2bf(v.z), f2bf(v.w) };
  *(us4*)dst = o;
}

// ---------------- GEMM: producer-consumer wave specialization ----------------
// (round-20 proven). 512 threads = 8 waves: waves 0-3 consumers (round-13
// fragment math), waves 4-7 producers (round-13 staging geometry).
// Double-buffered BK=64; producers fill buf^1 while consumers compute buf;
// __syncthreads makes each group wait only on ITS OWN counters -> producer
// vmcnt drain overlaps consumer compute.
// MODE 0: A=Xbf, B=Wqkv -> RoPE epilogue, Q (pre-scaled) / K row-major,
//         V transposed per head.  MODE 1: A=Obf, B=Wout -> fp32 out.
template <int MODE>
__global__ __launch_bounds__(512) void gemm_kernel(
    const unsigned short* __restrict__ A, const unsigned short* __restrict__ Bw,
    unsigned short* __restrict__ q_out, unsigned short* __restrict__ k_out,
    unsigned short* __restrict__ vt_out, const float2* __restrict__ rope,
    float* __restrict__ f_out) {
  constexpr int K = DMODEL;  // 1024
  __shared__ __align__(16) unsigned short As[2][2][128 * 32];  // [buf][kk] 32KB
  __shared__ __align__(16) unsigned short Bs[2][2][128 * 32];  // 32KB
  const int tid = threadIdx.x;
  const int l = tid & 63, w = tid >> 6;       // w 0..7
  const bool producer = (w >= 4);
  const int w4 = w & 3;                       // consumer wave id / producer id
  const int g = l >> 4, l15 = l & 15;

  // XCD-chunked swizzle (bijective)
  constexpr int GX  = (MODE == 0) ? 24 : 8;   // gridDim.x (n-blocks)
  constexpr int CHN = (MODE == 0) ? 12 : 4;   // n-blocks per XCD chunk
  const int lid = blockIdx.x + GX * blockIdx.y;
  const int xcd = lid & 7;
  const int sc  = lid >> 3;                   // slot in chunk
  const int bm = (xcd & 3) * 8 + (sc & 7);
  const int bn = (xcd >> 2) * CHN + (sc >> 3);
  const int m0 = bm * 128, n0 = bn * 128;
  const int wm = w4 >> 1, wn = w4 & 1;

  // producer staging addresses (round-13 geometry with pw = w4)
  const unsigned short* ag = A  + (size_t)(m0 + w4 * 16 + (l >> 2)) * K + (l & 3) * 8;
  const unsigned short* bg = Bw + (size_t)(n0 + w4 * 16 + (l >> 2)) * K + (l & 3) * 8;

  auto STAGE = [&](int bb, int kt) {
#pragma unroll
    for (int kk = 0; kk < 2; ++kk) {
      const unsigned short* a0 = ag + kt * 64 + kk * 32;
      const unsigned short* b0 = bg + kt * 64 + kk * 32;
      unsigned short* as0 = &As[bb][kk][0] + w4 * 512;
      unsigned short* bs0 = &Bs[bb][kk][0] + w4 * 512;
      gld_lds16(a0, as0);
      gld_lds16(a0 + (size_t)64 * K, as0 + 2048);
      gld_lds16(b0, bs0);
      gld_lds16(b0 + (size_t)64 * K, bs0 + 2048);
    }
  };

  const f32x4 zf = {0.f, 0.f, 0.f, 0.f};
  f32x4 acc[4][4];
#pragma unroll
  for (int i = 0; i < 4; ++i)
#pragma unroll
    for (int j = 0; j < 4; ++j) acc[i][j] = zf;

  if (producer) STAGE(0, 0);
  __syncthreads();
  int cur = 0;

  for (int kt = 0; kt < K / 64; ++kt) {
    if (producer) {
      if (kt + 1 < K / 64) STAGE(cur ^ 1, kt + 1);
    } else {
      bf16x8 af[4][2], bf[4][2];
#pragma unroll
      for (int i = 0; i < 4; ++i)
#pragma unroll
        for (int kk = 0; kk < 2; ++kk) {
          af[i][kk] = *(const bf16x8*)(&As[cur][kk][0] + (wm * 64 + i * 16 + l15) * 32 + g * 8);
          bf[i][kk] = *(const bf16x8*)(&Bs[cur][kk][0] + (wn * 64 + i * 16 + l15) * 32 + g * 8);
        }
#pragma unroll
      for (int i = 0; i < 4; ++i)
#pragma unroll
        for (int j = 0; j < 4; ++j) {
          acc[i][j] = __builtin_amdgcn_mfma_f32_16x16x32_bf16(af[i][0], bf[j][0], acc[i][j], 0, 0, 0);
          acc[i][j] = __builtin_amdgcn_mfma_f32_16x16x32_bf16(af[i][1], bf[j][1], acc[i][j], 0, 0, 0);
        }
    }
    __syncthreads();
    cur ^= 1;
  }

  if (producer) return;   // epilogue is consumer-only (waves 0-3 hold acc)

  if constexpr (MODE == 0) {
    const int region = n0 >> 10;  // 0=Q 1=K 2=V (128 | 1024 region boundaries)
    if (region <= 1) {
      unsigned short* outb = (region == 0) ? q_out : k_out;
      const float qs = (region == 0) ? QSCALE : 1.0f;
#pragma unroll
      for (int i = 0; i < 4; ++i) {
        const int mb = m0 + wm * 64 + i * 16 + g * 4;
#pragma unroll
        for (int j = 0; j < 4; ++j) {
          const int n = n0 + wn * 64 + j * 16 + l15;
          const int ncol = n & 1023;
          const int ip = (n & 63) >> 1;
          const float sgn = (n & 1) ? 1.f : -1.f;
#pragma unroll
          for (int r = 0; r < 4; ++r) {
            const int m = mb + r;
            const float v = acc[i][j][r];
            const float p = __shfl_xor(v, 1);  // partner column n^1
            const float2 cs = rope[m * 32 + ip];
            const float o = (v * cs.x + sgn * p * cs.y) * qs;
            outb[(size_t)m * DMODEL + ncol] = f2bf(o);
          }
        }
      }
    } else {  // V -> transposed per head: Vt[(b*1024 + h*64 + d)][l]
#pragma unroll
      for (int i = 0; i < 4; ++i) {
        const int mb = m0 + wm * 64 + i * 16 + g * 4;
        const int b = mb >> 11;
        const int lseq = mb & 2047;
#pragma unroll
        for (int j = 0; j < 4; ++j) {
          const int n = n0 + wn * 64 + j * 16 + l15;
          const int hd = n - 2048;
          us4 o = { f2bf(acc[i][j][0]), f2bf(acc[i][j][1]), f2bf(acc[i][j][2]), f2bf(acc[i][j][3]) };
          *(us4*)(vt_out + (size_t)(b * DMODEL + hd) * SEQ + lseq) = o;
        }
      }
    }
  } else {
#pragma unroll
    for (int i = 0; i < 4; ++i) {
      const int mb = m0 + wm * 64 + i * 16 + g * 4;
#pragma unroll
      for (int j = 0; j < 4; ++j) {
        const int n = n0 + wn * 64 + j * 16 + l15;
#pragma unroll
        for (int r = 0; r < 4; ++r) f_out[(size_t)(mb + r) * DMODEL + n] = acc[i][j][r];
      }
    }
  }
}

// ---------------- causal flash attention v13: producer-consumer waves ----------------
// (round-21 proven best: total 105.9us.) v12 math verbatim, 512 threads =
// 8 waves: waves 0-3 consumers (ITER/STORE, w = wfull&3), waves 4-7
// producers (STAGE via ptid = tid&255). Producers' vmcnt drains overlap
// consumers' QK->softmax->PV chain; plain __syncthreads handoff (counted
// vmcnt variants regressed -- 0-for-3 this session).
__global__ __launch_bounds__(512) void attn_kernel(
    const unsigned short* __restrict__ Qb, const unsigned short* __restrict__ Kb,
    const unsigned short* __restrict__ Vt, unsigned short* __restrict__ Ob) {
  __shared__ __align__(16) unsigned short kv[2][2][4096];  // [buf][K/V][64*64]
  __shared__ __align__(16) unsigned short Olds[4][16][72];
  const int tid = threadIdx.x;
  const int l = tid & 63;
  const int wfull = tid >> 6;            // 0..7
  const bool producer = (wfull >= 4);
  const int w = wfull & 3;               // q-subtile (consumer) / producer id
  const int g = l >> 4, q15 = l & 15;
  const int ptid = tid & 255;            // staging thread id (producers)

  // XCD-affinity remap (bijective): blocks of one bh share lid mod 8
  const int lid = blockIdx.x + 16 * blockIdx.y;   // 0..511
  const int xcd = lid & 7;
  const int slot = lid >> 3;                      // 0..63
  const int bh = xcd * 4 + (slot & 3);            // 0..31
  const int j = slot >> 2;                        // 0..15

  const int b = bh >> 4, h = bh & 15;
  const int tA = 31 - j;            // long phase q-tile
  const int tB = j;                 // short phase q-tile

  // Q fragments for both phases (consumers only)
  bf16x8 qA0{}, qA1{}, qB0{}, qB1{};
  if (!producer) {
    const unsigned short* qpA = Qb + (size_t)(b * SEQ + tA * 64 + w * 16 + q15) * DMODEL + h * DKH + g * 8;
    const unsigned short* qpB = Qb + (size_t)(b * SEQ + tB * 64 + w * 16 + q15) * DMODEL + h * DKH + g * 8;
    qA0 = *(const bf16x8*)qpA; qA1 = *(const bf16x8*)(qpA + 32);
    qB0 = *(const bf16x8*)qpB; qB1 = *(const bf16x8*)(qpB + 32);
  }
  const int qselA = tA * 64 + w * 16 + q15;
  const int qselB = tB * 64 + w * 16 + q15;

  // staging source (pre-swizzled), producers only: linear LDS slot
  // o = ptid*16 (+4096) holds tile element (row = o>>7,
  // colbyte = (o&127) ^ ((row&7)<<4))
  const int rS = ptid >> 3;                                       // rows 0..31 (+32)
  const int cS = (((ptid & 7) * 16) ^ ((rS & 7) << 4)) >> 1;      // element col
  const unsigned short* pKg = Kb + (size_t)(b * SEQ + rS) * DMODEL + h * DKH + cS;
  const unsigned short* pVg = Vt + (size_t)(b * DMODEL + h * DKH + rS) * SEQ + cS;

  // swizzled ds_read offsets (elements), reading row has row&7 == q15&7
  const int srow = (q15 & 7) << 4;
  const int oc0 = (srow ^ (g * 16)) >> 1;          // K frag: d-slice g*8..g*8+7
  const int oc1 = (srow ^ (g * 16 + 64)) >> 1;
  // V frag (K=16 A-operand): per blk, 8 bytes at col blk*32 + 8g
  int vc[4];
#pragma unroll
  for (int blk = 0; blk < 4; ++blk) vc[blk] = ((blk * 32 + 8 * g) ^ srow) >> 1;

  const f32x4 zf = {0.f, 0.f, 0.f, 0.f};
  float mrun = -1e30f, lrun = 0.f;   // lrun = per-lane partial row sum
  f32x4 ot[4];
#pragma unroll
  for (int d = 0; d < 4; ++d) ot[d] = zf;

  auto STAGE = [&](int bb, int k0) {   // producers only
    unsigned short* lk = &kv[bb][0][0] + w * 512;  // wave-uniform base (w = producer id)
    unsigned short* lv = &kv[bb][1][0] + w * 512;
    gld_lds16(pKg + (size_t)k0 * DMODEL, lk);
    gld_lds16(pKg + (size_t)(k0 + 32) * DMODEL, lk + 2048);
    gld_lds16(pVg + k0, lv);
    gld_lds16(pVg + (size_t)32 * SEQ + k0, lv + 2048);
  };

  auto STORE = [&](int qt) {           // role-aware; barrier hit by ALL waves
    if (!producer) {
      float lr = lrun;
      lr += __shfl_xor(lr, 16);
      lr += __shfl_xor(lr, 32);
      const float inv = 1.0f / lr;
#pragma unroll
      for (int d = 0; d < 4; ++d) {
        us4 o = { f2bf(ot[d][0] * inv), f2bf(ot[d][1] * inv), f2bf(ot[d][2] * inv), f2bf(ot[d][3] * inv) };
        *(us4*)&Olds[w][q15][d * 16 + g * 4] = o;
      }
    }
    __syncthreads();
    if (!producer) {
      const int r = l >> 2;
      const int c = (l & 3) * 16;
      const us8 v0 = *(const us8*)&Olds[w][r][c];
      const us8 v1 = *(const us8*)&Olds[w][r][c + 8];
      unsigned short* ob = Ob + (size_t)(b * SEQ + qt * 64 + w * 16 + r) * DMODEL + h * DKH + c;
      *(us8*)ob = v0;
      *(us8*)(ob + 8) = v1;
    }
  };

  // one k-tile: QK^T -> online softmax -> in-lane P pack -> K=16 PV.
  // Consumers only; domask is ALWAYS a literal at call sites.
  auto ITER = [&](int cur, int kb0, bf16x8 qf0, bf16x8 qf1, int qsel, bool domask) {
    const unsigned short* lkb = &kv[cur][0][0] + q15 * 64;
    const unsigned short* lvb = &kv[cur][1][0] + q15 * 64;

    float sp[4][4];
    float mt = -1e30f;
#pragma unroll
    for (int blk = 0; blk < 4; ++blk) {
      const bf16x8 kf0 = *(const bf16x8*)(lkb + blk * 1024 + oc0);
      const bf16x8 kf1 = *(const bf16x8*)(lkb + blk * 1024 + oc1);
      f32x4 c = zf;
      c = __builtin_amdgcn_mfma_f32_16x16x32_bf16(kf0, qf0, c, 0, 0, 0);
      c = __builtin_amdgcn_mfma_f32_16x16x32_bf16(kf1, qf1, c, 0, 0, 0);
#pragma unroll
      for (int r = 0; r < 4; ++r) {
        float s = c[r];  // already in exp2 domain (Q pre-scaled)
        if (domask && (kb0 + blk * 16 + g * 4 + r > qsel)) s = -1e30f;
        sp[blk][r] = s;
        mt = fmaxf(mt, s);
      }
    }
    mt = fmaxf(mt, __shfl_xor(mt, 16));
    mt = fmaxf(mt, __shfl_xor(mt, 32));

    const bool defer = __all(mt - mrun <= 8.0f);
    float mnew, alpha;
    if (defer) { mnew = mrun; alpha = 1.0f; }
    else { mnew = fmaxf(mrun, mt); alpha = fexp2(mrun - mnew); }

    float rs = 0.f;
#pragma unroll
    for (int blk = 0; blk < 4; ++blk)
#pragma unroll
      for (int r = 0; r < 4; ++r) {
        const float p = fexp2(sp[blk][r] - mnew);
        sp[blk][r] = p;
        rs += p;
      }
    if (defer) {
      lrun += rs;                 // per-lane partial; cross-lane reduce at STORE
    } else {
      lrun = lrun * alpha + rs;
      mrun = mnew;
#pragma unroll
      for (int d = 0; d < 4; ++d) ot[d] *= alpha;
    }

    // P -> bf16 K=16 B-fragments in-lane (no shuffles)
    short4v pfb[4];
#pragma unroll
    for (int blk = 0; blk < 4; ++blk) {
      union { __bf16 hh[4]; short4v v; } pk;
      pk.hh[0] = (__bf16)sp[blk][0];
      pk.hh[1] = (__bf16)sp[blk][1];
      pk.hh[2] = (__bf16)sp[blk][2];
      pk.hh[3] = (__bf16)sp[blk][3];
      pfb[blk] = pk.v;
    }

    // O^T[dt][q] += sum_blk Vt[16dt+q15][k(blk)] * P[k(blk)][q]  (K=16 MFMAs)
    __builtin_amdgcn_s_setprio(1);
#pragma unroll
    for (int dt = 0; dt < 4; ++dt) {
      const unsigned short* vrow = lvb + dt * 1024;
      f32x4 o = ot[dt];
#pragma unroll
      for (int blk = 0; blk < 4; ++blk) {
        const short4v vf = *(const short4v*)(vrow + vc[blk]);
        o = __builtin_amdgcn_mfma_f32_16x16x16bf16_1k(vf, pfb[blk], o, 0, 0, 0);
      }
      ot[dt] = o;
    }
    __builtin_amdgcn_s_setprio(0);
  };

  if (producer) STAGE(0, 0);
  __syncthreads();
  int cur = 0;

  // ---- phase A main (no mask) ----
  for (int i = 0; i < tA; ++i) {
    if (producer) STAGE(cur ^ 1, (i + 1) * 64);
    else ITER(cur, i * 64, qA0, qA1, qselA, false);
    __syncthreads();
    cur ^= 1;
  }
  // ---- phase A diagonal (mask) + prefetch phase-B tile 0 ----
  if (producer) STAGE(cur ^ 1, 0);
  else ITER(cur, tA * 64, qA0, qA1, qselA, true);
  STORE(tA);
  if (!producer) {
    mrun = -1e30f; lrun = 0.f;
#pragma unroll
    for (int d = 0; d < 4; ++d) ot[d] = zf;
  }
  __syncthreads();
  cur ^= 1;

  // ---- phase B main (no mask) ----
  for (int i = 0; i < tB; ++i) {
    if (producer) STAGE(cur ^ 1, (i + 1) * 64);
    else ITER(cur, i * 64, qB0, qB1, qselB, false);
    __syncthreads();
    cur ^= 1;
  }
  // ---- phase B diagonal (mask) ----
  if (!producer) ITER(cur, tB * 64, qB0, qB1, qselB, true);
  STORE(tB);
}

// ---------------- launch ----------------
extern "C" void kernel_launch(void* const* d_in, const int* in_sizes, int n_in,
                              void* d_out, int out_size, void* d_ws, size_t ws_size,
                              hipStream_t stream) {
  const float* X = (const float*)d_in[0];
  const int* pos = (const int*)d_in[1];
  const float* Wqkv = (const float*)d_in[2];
  const float* Wout = (const float*)d_in[3];
  char* ws = (char*)d_ws;
  unsigned short* xbf    = (unsigned short*)(ws + OFF_XBF);
  unsigned short* wqkvbf = (unsigned short*)(ws + OFF_WQKV);
  unsigned short* woutbf = (unsigned short*)(ws + OFF_WOUT);
  unsigned short* qb     = (unsigned short*)(ws + OFF_Q);
  unsigned short* kbuf   = (unsigned short*)(ws + OFF_K);
  unsigned short* vt     = (unsigned short*)(ws + OFF_VT);
  unsigned short* ob     = (unsigned short*)(ws + OFF_O);
  float2* rope           = (float2*)(ws + OFF_ROPE);

  prep_kernel<<<8192, 256, 0, stream>>>(X, Wqkv, Wout, pos, xbf, wqkvbf, woutbf, rope);
  gemm_kernel<0><<<dim3(NQKV / 128, MTOT / 128), 512, 0, stream>>>(
      xbf, wqkvbf, qb, kbuf, vt, rope, nullptr);
  attn_kernel<<<dim3(16, 32), 512, 0, stream>>>(qb, kbuf, vt, ob);
  gemm_kernel<1><<<dim3(DMODEL / 128, MTOT / 128), 512, 0, stream>>>(
      ob, woutbf, nullptr, nullptr, nullptr, nullptr, (float*)d_out);
}